// Round 2
// baseline (287.538 us; speedup 1.0000x reference)
//
#include <hip/hip_runtime.h>
#include <hip/hip_bf16.h>
#include <cstdint>
#include <cstddef>

#define DIMD 1024
#define LSEQ 4096
#define BATCH 4
#define MTOT (BATCH*LSEQ)          // 16384
#define NCHUNK 64
#define CHUNKLEN 64                // NCHUNK*CHUNKLEN == LSEQ
#define GATE_ELEMS ((size_t)MTOT*DIMD)

typedef __bf16 bf16x8 __attribute__((ext_vector_type(8)));
typedef float f32x4 __attribute__((ext_vector_type(4)));

__device__ __forceinline__ unsigned short f2bf(float f) {
    union { float f; uint32_t u; } v; v.f = f;
    uint32_t r = v.u + 0x7fffu + ((v.u >> 16) & 1u);   // RNE
    return (unsigned short)(r >> 16);
}
__device__ __forceinline__ float bits2f(unsigned short b) {
    union { uint32_t u; float f; } v; v.u = ((uint32_t)b) << 16; return v.f;
}
// gate-array load/store, dtype-generic (float = fp32 path, ushort = bf16 path)
__device__ __forceinline__ float gld(const float* p, size_t o) { return p[o]; }
__device__ __forceinline__ float gld(const unsigned short* p, size_t o) { return bits2f(p[o]); }
__device__ __forceinline__ void  gst(float* p, size_t o, float v) { p[o] = v; }
__device__ __forceinline__ void  gst(unsigned short* p, size_t o, float v) { p[o] = f2bf(v); }

// ---------------- cast fp32 -> bf16 (vectorized 8/thread) ----------------
__global__ void cast_f32_to_bf16(const float* __restrict__ src,
                                 unsigned short* __restrict__ dst, int n) {
    int i = (blockIdx.x * blockDim.x + threadIdx.x) * 8;
    if (i >= n) return;
    float4 a = *(const float4*)(src + i);
    float4 b = *(const float4*)(src + i + 4);
    uint4 o;
    o.x = (uint32_t)f2bf(a.x) | ((uint32_t)f2bf(a.y) << 16);
    o.y = (uint32_t)f2bf(a.z) | ((uint32_t)f2bf(a.w) << 16);
    o.z = (uint32_t)f2bf(b.x) | ((uint32_t)f2bf(b.y) << 16);
    o.w = (uint32_t)f2bf(b.z) | ((uint32_t)f2bf(b.w) << 16);
    *(uint4*)(dst + i) = o;
}

// ---------------- fused 4-gate GEMM (m97 structure, 128x128 tile, BK=64) ----------------
// C[m,n] = sum_k Xb[m,k]*Wcat[n,k];  n in [0,4096), gate = n>>10.
// Epilogue: +bias, activation (gate1 -> tanh, else sigmoid), store G[gate][m][e] as T.
template <typename T>
__global__ __launch_bounds__(256, 2) void gemm_gates(
    const unsigned short* __restrict__ Xb,    // [16384][1024] bf16 bits
    const unsigned short* __restrict__ Wcat,  // [4096][1024]  bf16 bits
    const float* __restrict__ bf_, const float* __restrict__ bi_,
    const float* __restrict__ big_, const float* __restrict__ bog_,
    T* __restrict__ G)                        // [4][16384][1024]
{
    __shared__ __align__(16) unsigned short As[128 * 64];  // 16 KB
    __shared__ __align__(16) unsigned short Bs[128 * 64];  // 16 KB
    const int tid = threadIdx.x;
    const int wave = tid >> 6, lane = tid & 63;
    const int m0 = blockIdx.x * 128;
    const int n0 = blockIdx.y * 128;
    const int wr = wave >> 1, wc = wave & 1;
    const int l15 = lane & 15, l4 = lane >> 4;

    f32x4 acc[4][4];
#pragma unroll
    for (int m = 0; m < 4; ++m)
#pragma unroll
        for (int n = 0; n < 4; ++n) acc[m][n] = (f32x4)0.f;

    for (int k0 = 0; k0 < DIMD; k0 += 64) {
        // stage A and B tiles: 16 KB each, 4 rounds of (256 thr x 16 B)
#pragma unroll
        for (int r = 0; r < 4; ++r) {
            int elem = r * 2048 + wave * 512 + lane * 8;  // element index into [128][64]
            int row = elem >> 6, col = elem & 63;
            __builtin_amdgcn_global_load_lds(
                (const __attribute__((address_space(1))) uint32_t*)(Xb + (size_t)(m0 + row) * DIMD + k0 + col),
                (__attribute__((address_space(3))) uint32_t*)(As + r * 2048 + wave * 512),
                16, 0, 0);
            __builtin_amdgcn_global_load_lds(
                (const __attribute__((address_space(1))) uint32_t*)(Wcat + (size_t)(n0 + row) * DIMD + k0 + col),
                (__attribute__((address_space(3))) uint32_t*)(Bs + r * 2048 + wave * 512),
                16, 0, 0);
        }
        __syncthreads();
#pragma unroll
        for (int kk = 0; kk < 2; ++kk) {
            bf16x8 av[4], bv[4];
#pragma unroll
            for (int m = 0; m < 4; ++m)
                av[m] = *(const bf16x8*)(As + (wr * 64 + m * 16 + l15) * 64 + kk * 32 + l4 * 8);
#pragma unroll
            for (int n = 0; n < 4; ++n)
                bv[n] = *(const bf16x8*)(Bs + (wc * 64 + n * 16 + l15) * 64 + kk * 32 + l4 * 8);
#pragma unroll
            for (int m = 0; m < 4; ++m)
#pragma unroll
                for (int n = 0; n < 4; ++n)
                    acc[m][n] = __builtin_amdgcn_mfma_f32_16x16x32_bf16(av[m], bv[n], acc[m][n], 0, 0, 0);
        }
        __syncthreads();
    }

    const int gate = n0 >> 10;
    const float* bias = (gate == 0) ? bf_ : (gate == 1) ? bi_ : (gate == 2) ? big_ : bog_;
    T* Gg = G + (size_t)gate * GATE_ELEMS;
    const int ecol = (n0 & 1023) + wc * 64;
#pragma unroll
    for (int n = 0; n < 4; ++n) {
        int e = ecol + n * 16 + l15;
        float bvv = bias[e];
#pragma unroll
        for (int m = 0; m < 4; ++m) {
            int rowb = m0 + wr * 64 + m * 16 + l4 * 4;
#pragma unroll
            for (int r = 0; r < 4; ++r) {
                float pre = acc[m][n][r] + bvv;
                float v = (gate == 1) ? tanhf(pre) : 1.f / (1.f + __expf(-pre));
                gst(Gg, (size_t)(rowb + r) * DIMD + e, v);
            }
        }
    }
}

// ---------------- scan phase 1: per-chunk affine aggregates ----------------
template <typename T>
__global__ void scan_phase1(const T* __restrict__ F, const T* __restrict__ TI,
                            const T* __restrict__ SG,
                            float* __restrict__ Aagg, float* __restrict__ Bagg) {
    const int d = blockIdx.x * blockDim.x + threadIdx.x;  // 0..1023
    const int c = blockIdx.y, b = blockIdx.z;
    size_t base = ((size_t)b * LSEQ + (size_t)c * CHUNKLEN) * DIMD + d;
    float A = 1.f, Bv = 0.f;
#pragma unroll 8
    for (int t = 0; t < CHUNKLEN; ++t) {
        size_t off = base + (size_t)t * DIMD;
        float f = gld(F, off);
        float i = gld(TI, off) * gld(SG, off);
        A *= f;
        Bv = __builtin_fmaf(f, Bv, i);
    }
    size_t o = ((size_t)b * NCHUNK + c) * DIMD + d;
    Aagg[o] = A;
    Bagg[o] = Bv;
}

// ---------------- scan phase 2: sequential scan over chunk aggregates ----------------
__global__ void scan_phase2(const float* __restrict__ Aagg, const float* __restrict__ Bagg,
                            const float* __restrict__ hidden,
                            float* __restrict__ Hstart, float* __restrict__ out_h) {
    int idx = blockIdx.x * blockDim.x + threadIdx.x;  // 0..4095
    int b = idx >> 10, d = idx & 1023;
    float h = hidden[b * 1024 + d];
    for (int c = 0; c < NCHUNK; ++c) {
        size_t o = ((size_t)b * NCHUNK + c) * DIMD + d;
        Hstart[o] = h;
        h = __builtin_fmaf(Aagg[o], h, Bagg[o]);
    }
    out_h[b * 1024 + d] = h;
}

// ---------------- scan phase 3: replay chunk with prefix, write y ----------------
template <typename T>
__global__ void scan_phase3(const T* __restrict__ F, const T* __restrict__ TI,
                            const T* __restrict__ SG, const T* __restrict__ OG,
                            const float* __restrict__ Hstart, float* __restrict__ y) {
    const int d = blockIdx.x * blockDim.x + threadIdx.x;
    const int c = blockIdx.y, b = blockIdx.z;
    float h = Hstart[((size_t)b * NCHUNK + c) * DIMD + d];
    size_t base = ((size_t)b * LSEQ + (size_t)c * CHUNKLEN) * DIMD + d;
#pragma unroll 4
    for (int t = 0; t < CHUNKLEN; ++t) {
        size_t off = base + (size_t)t * DIMD;
        float f = gld(F, off);
        float i = gld(TI, off) * gld(SG, off);
        h = __builtin_fmaf(f, h, i);
        y[off] = tanhf(h) * gld(OG, off);
    }
}

// ---------------- launch ----------------
extern "C" void kernel_launch(void* const* d_in, const int* in_sizes, int n_in,
                              void* d_out, int out_size, void* d_ws, size_t ws_size,
                              hipStream_t stream) {
    const float* x      = (const float*)d_in[0];
    const float* hidden = (const float*)d_in[1];
    const float* Wf  = (const float*)d_in[2];
    const float* bf_ = (const float*)d_in[3];
    const float* Wi  = (const float*)d_in[4];
    const float* bi_ = (const float*)d_in[5];
    const float* Wig = (const float*)d_in[6];
    const float* big_= (const float*)d_in[7];
    const float* Wog = (const float*)d_in[8];
    const float* bog_= (const float*)d_in[9];

    char* ws = (char*)d_ws;
    unsigned short* Xb   = (unsigned short*)(ws);            // 33,554,432 B
    unsigned short* Wcat = (unsigned short*)(ws + 33554432); //  8,388,608 B
    // gates start at 41,943,040

    float* y     = (float*)d_out;                 // [4][4096][1024]
    float* out_h = y + GATE_ELEMS;                // [4][1024]

    // casts (shared by both paths)
    cast_f32_to_bf16<<<MTOT * DIMD / 8 / 256, 256, 0, stream>>>(x, Xb, MTOT * DIMD);
    cast_f32_to_bf16<<<DIMD * DIMD / 8 / 256, 256, 0, stream>>>(Wf,  Wcat + 0 * DIMD * DIMD, DIMD * DIMD);
    cast_f32_to_bf16<<<DIMD * DIMD / 8 / 256, 256, 0, stream>>>(Wi,  Wcat + 1 * DIMD * DIMD, DIMD * DIMD);
    cast_f32_to_bf16<<<DIMD * DIMD / 8 / 256, 256, 0, stream>>>(Wig, Wcat + 2 * DIMD * DIMD, DIMD * DIMD);
    cast_f32_to_bf16<<<DIMD * DIMD / 8 / 256, 256, 0, stream>>>(Wog, Wcat + 3 * DIMD * DIMD, DIMD * DIMD);

    const size_t FP32_WS_NEED = 33554432ull + 8388608ull + GATE_ELEMS * 4 * 4 + 3ull * 1048576ull; // 313,524,224
    if (ws_size >= FP32_WS_NEED) {
        // -------- fp32-gate path --------
        float* G      = (float*)(ws + 41943040);             // 268,435,456 B
        float* Aagg   = (float*)(ws + 310378496);
        float* Bagg   = (float*)(ws + 311427072);
        float* Hstart = (float*)(ws + 312475648);
        gemm_gates<float><<<dim3(MTOT / 128, 4096 / 128), 256, 0, stream>>>(
            Xb, Wcat, bf_, bi_, big_, bog_, G);
        const float* Fg  = G;
        const float* TIg = G + 1 * GATE_ELEMS;
        const float* SGg = G + 2 * GATE_ELEMS;
        const float* OGg = G + 3 * GATE_ELEMS;
        scan_phase1<float><<<dim3(DIMD / 256, NCHUNK, BATCH), 256, 0, stream>>>(Fg, TIg, SGg, Aagg, Bagg);
        scan_phase2<<<BATCH * DIMD / 256, 256, 0, stream>>>(Aagg, Bagg, hidden, Hstart, out_h);
        scan_phase3<float><<<dim3(DIMD / 256, NCHUNK, BATCH), 256, 0, stream>>>(Fg, TIg, SGg, OGg, Hstart, y);
    } else {
        // -------- bf16-gate path (ws need: 179,306,496 B = 171 MiB) --------
        unsigned short* G = (unsigned short*)(ws + 41943040);   // 134,217,728 B
        float* Aagg   = (float*)(ws + 176160768);
        float* Bagg   = (float*)(ws + 177209344);
        float* Hstart = (float*)(ws + 178257920);
        gemm_gates<unsigned short><<<dim3(MTOT / 128, 4096 / 128), 256, 0, stream>>>(
            Xb, Wcat, bf_, bi_, big_, bog_, G);
        const unsigned short* Fg  = G;
        const unsigned short* TIg = G + 1 * GATE_ELEMS;
        const unsigned short* SGg = G + 2 * GATE_ELEMS;
        const unsigned short* OGg = G + 3 * GATE_ELEMS;
        scan_phase1<unsigned short><<<dim3(DIMD / 256, NCHUNK, BATCH), 256, 0, stream>>>(Fg, TIg, SGg, Aagg, Bagg);
        scan_phase2<<<BATCH * DIMD / 256, 256, 0, stream>>>(Aagg, Bagg, hidden, Hstart, out_h);
        scan_phase3<unsigned short><<<dim3(DIMD / 256, NCHUNK, BATCH), 256, 0, stream>>>(Fg, TIg, SGg, OGg, Hstart, y);
    }
}